// Round 5
// baseline (9186.575 us; speedup 1.0000x reference)
//
#include <hip/hip_runtime.h>
#include <hip/hip_bf16.h>

#define Tz  512
#define Hz  512
#define BHz (256*512)
#define NBLK 192

typedef __bf16 bf16x8 __attribute__((ext_vector_type(8)));
typedef float  f32x4  __attribute__((ext_vector_type(4)));

#define MFMA16(A,B,C) __builtin_amdgcn_mfma_f32_16x16x32_bf16(A,B,C,0,0,0)

__device__ __forceinline__ float sigf(float x){ return 1.0f/(1.0f+__expf(-x)); }
__device__ __forceinline__ float tanhf_(float x){ return 2.0f/(1.0f+__expf(-2.0f*x)) - 1.0f; }

// coherent (agent-scope, L3-backed) 8B accesses — no cache-wide fences needed
__device__ __forceinline__ unsigned long long cload(const unsigned long long* p){
    return __hip_atomic_load(p, __ATOMIC_RELAXED, __HIP_MEMORY_SCOPE_AGENT);
}
__device__ __forceinline__ void cstore(unsigned long long* p, unsigned long long v){
    __hip_atomic_store(p, v, __ATOMIC_RELAXED, __HIP_MEMORY_SCOPE_AGENT);
}

// ---- pack weights as MFMA *A*-operand frags (W^T), gate-interleaved cols ----
// packed col within 16-wide tile: cc = jl*4 + gate  (jl = j offset 0..3)
// layout [jt][kb][lane][i]: value = W[kb*32 + (lane>>4)*8 + i][gate*512 + jt*4 + jl]
__global__ void pack_w1(const float* __restrict__ w, __bf16* __restrict__ out){
    int idx = blockIdx.x*256 + threadIdx.x;   // 1,048,576 = 128*16*64*8
    int i = idx & 7, lane = (idx>>3)&63, kb = (idx>>9)&15, jt = idx>>13;
    int k  = kb*32 + (lane>>4)*8 + i;
    int m  = lane & 15;
    int col = (m&3)*512 + jt*4 + (m>>2);
    out[idx] = (__bf16)w[k*2048 + col];
}

__global__ void pack_w2(const float* __restrict__ wih, const float* __restrict__ whh,
                        __bf16* __restrict__ out){
    int idx = blockIdx.x*256 + threadIdx.x;   // 2,097,152 = 128*32*64*8
    int i = idx & 7, lane = (idx>>3)&63, kb = (idx>>9)&31, jt = idx>>14;
    int k  = kb*32 + (lane>>4)*8 + i;
    int m  = lane & 15;
    int col = (m&3)*512 + jt*4 + (m>>2);
    float val = (k < 512) ? wih[k*2048 + col] : whh[(k-512)*2048 + col];
    out[idx] = (__bf16)val;
}

__global__ void pack_bias(const float* a, const float* b, const float* c, const float* d,
                          float* b1s, float* b2s){
    int i = blockIdx.x*256 + threadIdx.x;
    if (i < 2048){ b1s[i] = a[i]+b[i]; b2s[i] = c[i]+d[i]; }
}

// ---- per-band tree barrier: 48 blocks = 8 subs x 6; relaxed atomics only ----
// __syncthreads drains vmcnt(0) for every wave -> all coherent h-stores are
// globally visible before the leader's arrival add. No buffer_wbl2/inv.
__device__ __forceinline__ void band_barrier(unsigned* base, int sub, unsigned target){
    asm volatile("s_waitcnt vmcnt(0)" ::: "memory");
    __syncthreads();
    if (threadIdx.x == 0){
        unsigned old = __hip_atomic_fetch_add(base + sub*16, 1u, __ATOMIC_RELAXED, __HIP_MEMORY_SCOPE_AGENT);
        if (old == target*6u - 1u){
            unsigned o2 = __hip_atomic_fetch_add(base + 128, 1u, __ATOMIC_RELAXED, __HIP_MEMORY_SCOPE_AGENT);
            if (o2 == target*8u - 1u)
                __hip_atomic_store(base + 144, target, __ATOMIC_RELAXED, __HIP_MEMORY_SCOPE_AGENT);
        }
        while (__hip_atomic_load(base + 144, __ATOMIC_RELAXED, __HIP_MEMORY_SCOPE_AGENT) < target)
            __builtin_amdgcn_s_sleep(1);
    }
    __syncthreads();
}

// ---- stage one band (64 rows x 512 bf16 = 64KB) into LDS, XOR-swizzled ----
// slot16 index = (r*64 + kc) ^ (r&7) : read side uses the same XOR.
__device__ __forceinline__ void stage_h(bf16x8* sh, const unsigned long long* src, int tid){
    #pragma unroll
    for (int i = 0; i < 16; ++i){
        int c  = tid + 256*i;
        int r  = c >> 6;
        int kc = c & 63;
        union { unsigned long long u[2]; bf16x8 v; } U;
        U.u[0] = cload(src + r*128 + kc*2);
        U.u[1] = cload(src + r*128 + kc*2 + 1);
        sh[c ^ (r & 7)] = U.v;
    }
}

// ---- persistent 2-layer LSTM; 192 blocks x 256 thr ----
// band g = bid&3 (64 batch rows); t = bid>>2: t<16 -> layer1 (32 j), else layer2 (16 j).
// MFMA: D = W_frag (A) x h_frag (B); lane: batch row = lane&15, j = jt*4 + (lane>>4),
// gates i,f,g,o = acc components q=0..3. Weights live in VGPRs for all 512 steps.
__launch_bounds__(256, 2)
__global__ void lstm_persistent(const float* __restrict__ x,      // [B][T][2]
                                const float* __restrict__ wih1,   // [2][2048]
                                const float* __restrict__ b1s,
                                const float* __restrict__ b2s,
                                const __bf16* __restrict__ w1p,
                                const __bf16* __restrict__ w2p,
                                __bf16* __restrict__ h1b,         // 2 x [B][H]
                                __bf16* __restrict__ h2b,         // 2 x [B][H]
                                unsigned* __restrict__ bar)       // [4][256]
{
    __shared__ bf16x8 sh[4096];   // 64 KB
    const int bid = blockIdx.x;
    const int g   = bid & 3;
    const int t   = bid >> 2;            // 0..47
    const int sub = t & 7;
    unsigned* gbar = bar + g*256;

    const int tid  = threadIdx.x;
    const int v    = tid >> 6;
    const int lane = tid & 63;
    const int llo  = lane & 15, lhi = lane >> 4;
    const int sw   = llo & 7;

    const unsigned long long* h1u = (const unsigned long long*)h1b;
    const unsigned long long* h2u = (const unsigned long long*)h2b;
    const size_t bandoff = (size_t)g*64*128;       // ull offset of band start
    const int HB = BHz/4;                          // ulls per h buffer

    if (t < 16){
        // ---------------- layer 1 ----------------
        const int jb0 = t*8 + v*2;                 // wave owns jtiles jb0, jb0+1
        bf16x8 wf[2][16];
        #pragma unroll
        for (int m = 0; m < 2; ++m)
            #pragma unroll
            for (int kb = 0; kb < 16; ++kb)
                wf[m][kb] = *reinterpret_cast<const bf16x8*>(
                    w1p + ((size_t)((jb0+m)*16 + kb)*64 + lane)*8);
        float wa[2][4], wb[2][4], bb[2][4];
        #pragma unroll
        for (int m = 0; m < 2; ++m)
            #pragma unroll
            for (int q = 0; q < 4; ++q){
                int col = q*512 + (jb0+m)*4 + lhi;
                wa[m][q] = wih1[col]; wb[m][q] = wih1[2048 + col]; bb[m][q] = b1s[col];
            }
        const float2* x2 = reinterpret_cast<const float2*>(x);
        float c1[2][4] = {{0,0,0,0},{0,0,0,0}};

        for (int p = 0; p <= Tz; ++p){
            if (p < Tz){
                stage_h(sh, h1u + ((p+1)&1)*HB + bandoff, tid);
                __syncthreads();
                f32x4 acc[2][4];
                #pragma unroll
                for (int m = 0; m < 2; ++m)
                    #pragma unroll
                    for (int nt = 0; nt < 4; ++nt) acc[m][nt] = (f32x4){0,0,0,0};
                #pragma unroll
                for (int nt = 0; nt < 4; ++nt){
                    const int rb = (nt*16 + llo) << 6;
                    #pragma unroll
                    for (int kb = 0; kb < 16; ++kb){
                        bf16x8 bf = sh[(rb + kb*4 + lhi) ^ sw];
                        acc[0][nt] = MFMA16(wf[0][kb], bf, acc[0][nt]);
                        acc[1][nt] = MFMA16(wf[1][kb], bf, acc[1][nt]);
                    }
                }
                unsigned long long* h1n = (unsigned long long*)h1b + (p&1)*HB;
                #pragma unroll
                for (int nt = 0; nt < 4; ++nt){
                    int row = g*64 + nt*16 + llo;
                    float2 xv = x2[(size_t)row*Tz + p];
                    #pragma unroll
                    for (int m = 0; m < 2; ++m){
                        float gi = acc[m][nt][0] + xv.x*wa[m][0] + xv.y*wb[m][0] + bb[m][0];
                        float gf = acc[m][nt][1] + xv.x*wa[m][1] + xv.y*wb[m][1] + bb[m][1];
                        float gg = acc[m][nt][2] + xv.x*wa[m][2] + xv.y*wb[m][2] + bb[m][2];
                        float go = acc[m][nt][3] + xv.x*wa[m][3] + xv.y*wb[m][3] + bb[m][3];
                        float cn = sigf(gf)*c1[m][nt] + sigf(gi)*tanhf_(gg);
                        c1[m][nt] = cn;
                        __bf16 hv = (__bf16)(sigf(go)*tanhf_(cn));
                        unsigned hbv;
                        { union { __bf16 b; unsigned short s; } C; C.b = hv; hbv = C.s; }
                        unsigned s1 = __shfl(hbv, llo+16, 64);
                        unsigned s2 = __shfl(hbv, llo+32, 64);
                        unsigned s3 = __shfl(hbv, llo+48, 64);
                        if (lane < 16){
                            unsigned long long pk = (unsigned long long)hbv
                                | ((unsigned long long)s1 << 16)
                                | ((unsigned long long)s2 << 32)
                                | ((unsigned long long)s3 << 48);
                            cstore(h1n + (size_t)row*128 + (jb0+m), pk);
                        }
                    }
                }
            }
            band_barrier(gbar, sub, (unsigned)(p+1));
        }
    } else {
        // ---------------- layer 2 ----------------
        const int b2 = t - 16;                      // 0..31
        const int jt = b2*4 + v;                    // 0..127
        bf16x8 wf[32];
        #pragma unroll
        for (int kb = 0; kb < 32; ++kb)
            wf[kb] = *reinterpret_cast<const bf16x8*>(
                w2p + ((size_t)(jt*32 + kb)*64 + lane)*8);
        float bb2[4];
        #pragma unroll
        for (int q = 0; q < 4; ++q) bb2[q] = b2s[q*512 + jt*4 + lhi];
        float c2[4] = {0,0,0,0};

        for (int p = 0; p <= Tz; ++p){
            if (p >= 1){
                f32x4 acc[4];
                #pragma unroll
                for (int nt = 0; nt < 4; ++nt) acc[nt] = (f32x4){0,0,0,0};
                // half 1: K from h1[p-1]
                stage_h(sh, h1u + ((p+1)&1)*HB + bandoff, tid);
                __syncthreads();
                #pragma unroll
                for (int nt = 0; nt < 4; ++nt){
                    const int rb = (nt*16 + llo) << 6;
                    #pragma unroll
                    for (int kb = 0; kb < 16; ++kb){
                        bf16x8 bf = sh[(rb + kb*4 + lhi) ^ sw];
                        acc[nt] = MFMA16(wf[kb], bf, acc[nt]);
                    }
                }
                __syncthreads();
                // half 2: K from h2[p-2]
                stage_h(sh, h2u + (p&1)*HB + bandoff, tid);
                __syncthreads();
                #pragma unroll
                for (int nt = 0; nt < 4; ++nt){
                    const int rb = (nt*16 + llo) << 6;
                    #pragma unroll
                    for (int kb = 16; kb < 32; ++kb){
                        bf16x8 bf = sh[(rb + (kb-16)*4 + lhi) ^ sw];
                        acc[nt] = MFMA16(wf[kb], bf, acc[nt]);
                    }
                }
                unsigned long long* h2n = (unsigned long long*)h2b + ((p+1)&1)*HB;
                #pragma unroll
                for (int nt = 0; nt < 4; ++nt){
                    int row = g*64 + nt*16 + llo;
                    float gi = acc[nt][0] + bb2[0];
                    float gf = acc[nt][1] + bb2[1];
                    float gg = acc[nt][2] + bb2[2];
                    float go = acc[nt][3] + bb2[3];
                    float cn = sigf(gf)*c2[nt] + sigf(gi)*tanhf_(gg);
                    c2[nt] = cn;
                    __bf16 hv = (__bf16)(sigf(go)*tanhf_(cn));
                    unsigned hbv;
                    { union { __bf16 b; unsigned short s; } C; C.b = hv; hbv = C.s; }
                    unsigned s1 = __shfl(hbv, llo+16, 64);
                    unsigned s2 = __shfl(hbv, llo+32, 64);
                    unsigned s3 = __shfl(hbv, llo+48, 64);
                    if (lane < 16){
                        unsigned long long pk = (unsigned long long)hbv
                            | ((unsigned long long)s1 << 16)
                            | ((unsigned long long)s2 << 32)
                            | ((unsigned long long)s3 << 48);
                        cstore(h2n + (size_t)row*128 + jt, pk);
                    }
                }
            }
            band_barrier(gbar, sub, (unsigned)(p+1));
        }
    }
}

// ---- final logits + softmax ----
__global__ void logits_softmax(const __bf16* __restrict__ h2, const float* __restrict__ fcw,
                               const float* __restrict__ fcb, float* __restrict__ out)
{
    int row = blockIdx.x;
    int lane = threadIdx.x;
    float acc[11];
    #pragma unroll
    for (int o = 0; o < 11; ++o) acc[o] = 0.f;
    for (int it = 0; it < 8; ++it){
        int jj = it*64 + lane;
        float hv = (float)h2[row*512 + jj];
        #pragma unroll
        for (int o = 0; o < 11; ++o) acc[o] += hv * fcw[jj*11 + o];
    }
    #pragma unroll
    for (int o = 0; o < 11; ++o)
        for (int s = 32; s >= 1; s >>= 1) acc[o] += __shfl_xor(acc[o], s, 64);
    float m = -1e30f;
    #pragma unroll
    for (int o = 0; o < 11; ++o){ acc[o] += fcb[o]; m = fmaxf(m, acc[o]); }
    float ssum = 0.f;
    #pragma unroll
    for (int o = 0; o < 11; ++o){ acc[o] = __expf(acc[o] - m); ssum += acc[o]; }
    float inv = 1.0f/ssum;
    if (lane < 11) out[row*11 + lane] = acc[lane]*inv;
}

extern "C" void kernel_launch(void* const* d_in, const int* in_sizes, int n_in,
                              void* d_out, int out_size, void* d_ws, size_t ws_size,
                              hipStream_t stream)
{
    const float* x    = (const float*)d_in[0];
    const float* wih1 = (const float*)d_in[1];
    const float* whh1 = (const float*)d_in[2];
    const float* bih1 = (const float*)d_in[3];
    const float* bhh1 = (const float*)d_in[4];
    const float* wih2 = (const float*)d_in[5];
    const float* whh2 = (const float*)d_in[6];
    const float* bih2 = (const float*)d_in[7];
    const float* bhh2 = (const float*)d_in[8];
    const float* fcw  = (const float*)d_in[9];
    const float* fcb  = (const float*)d_in[10];
    float* out = (float*)d_out;

    char* p = (char*)d_ws;
    __bf16* w1p = (__bf16*)p;  p += (size_t)512*2048*2;   // 2 MB
    __bf16* w2p = (__bf16*)p;  p += (size_t)1024*2048*2;  // 4 MB
    float*  b1s = (float*)p;   p += 2048*4;
    float*  b2s = (float*)p;   p += 2048*4;
    __bf16* h1b = (__bf16*)p;  p += (size_t)2*BHz*2;      // 512 KB
    __bf16* h2b = (__bf16*)p;  p += (size_t)2*BHz*2;      // 512 KB
    unsigned* bar = (unsigned*)p; p += 4*256*4;           // 4 KB

    hipMemsetAsync(h1b, 0, (size_t)2*BHz*2, stream);
    hipMemsetAsync(h2b, 0, (size_t)2*BHz*2, stream);
    hipMemsetAsync(bar, 0, 4*256*4, stream);
    pack_w1 <<<4096, 256, 0, stream>>>(whh1, w1p);
    pack_w2 <<<8192, 256, 0, stream>>>(wih2, whh2, w2p);
    pack_bias<<<8,   256, 0, stream>>>(bih1, bhh1, bih2, bhh2, b1s, b2s);

    // 192 blocks, 64KB LDS each -> at most 2/CU, always fully co-resident.
    lstm_persistent<<<NBLK, 256, 0, stream>>>(x, wih1, b1s, b2s, w1p, w2p, h1b, h2b, bar);

    logits_softmax<<<256, 64, 0, stream>>>(h2b + BHz, fcw, fcb, out);
}

// Round 6
// 5113.820 us; speedup vs baseline: 1.7964x; 1.7964x over previous
//
#include <hip/hip_runtime.h>
#include <hip/hip_bf16.h>

#define Tz  512
#define Hz  512
#define BHz (256*512)
#define NBLK 192
#define BPB  24          // blocks per band (8 L1 + 16 L2)
#define PROBE_IT 128

typedef __bf16 bf16x8 __attribute__((ext_vector_type(8)));
typedef float  f32x4  __attribute__((ext_vector_type(4)));
typedef unsigned long long ull;

#define MFMA16(A,B,C) __builtin_amdgcn_mfma_f32_16x16x32_bf16(A,B,C,0,0,0)

__device__ __forceinline__ float sigf(float x){ return 1.0f/(1.0f+__expf(-x)); }
__device__ __forceinline__ float tanhf_(float x){ return 2.0f/(1.0f+__expf(-2.0f*x)) - 1.0f; }

// coherent (L2-bypassing, L3-backed) 8B ops
__device__ __forceinline__ ull cload(const ull* p){
    return __hip_atomic_load(p, __ATOMIC_RELAXED, __HIP_MEMORY_SCOPE_AGENT);
}
__device__ __forceinline__ void cstore(ull* p, ull v){
    __hip_atomic_store(p, v, __ATOMIC_RELAXED, __HIP_MEMORY_SCOPE_AGENT);
}

// ---- pack weights as MFMA A-operand frags (W^T), gate-interleaved (r5-verified) ----
__global__ void pack_w1(const float* __restrict__ w, __bf16* __restrict__ out){
    int idx = blockIdx.x*256 + threadIdx.x;   // 1,048,576 = 128*16*64*8
    int i = idx & 7, lane = (idx>>3)&63, kb = (idx>>9)&15, jt = idx>>13;
    int k  = kb*32 + (lane>>4)*8 + i;
    int m  = lane & 15;
    int col = (m&3)*512 + jt*4 + (m>>2);
    out[idx] = (__bf16)w[k*2048 + col];
}
__global__ void pack_w2(const float* __restrict__ wih, const float* __restrict__ whh,
                        __bf16* __restrict__ out){
    int idx = blockIdx.x*256 + threadIdx.x;   // 2,097,152 = 128*32*64*8
    int i = idx & 7, lane = (idx>>3)&63, kb = (idx>>9)&31, jt = idx>>14;
    int k  = kb*32 + (lane>>4)*8 + i;
    int m  = lane & 15;
    int col = (m&3)*512 + jt*4 + (m>>2);
    float val = (k < 512) ? wih[k*2048 + col] : whh[(k-512)*2048 + col];
    out[idx] = (__bf16)val;
}
__global__ void pack_bias(const float* a, const float* b, const float* c, const float* d,
                          float* b1s, float* b2s){
    int i = blockIdx.x*256 + threadIdx.x;
    if (i < 2048){ b1s[i] = a[i]+b[i]; b2s[i] = c[i]+d[i]; }
}

// ---- stage 32 rows x 512 bf16 (32 KB) into LDS, XOR-swizzled ----
__device__ __forceinline__ void stage32(bf16x8* sh, const ull* src, int tid){
    #pragma unroll
    for (int i = 0; i < 8; ++i){
        int c = tid + 256*i;            // slot 0..2047
        int r = c >> 6;                 // row 0..31
        union { ull u[2]; bf16x8 v; } U;
        U.u[0] = cload(src + (size_t)r*128 + (size_t)(c&63)*2);
        U.u[1] = cload(src + (size_t)r*128 + (size_t)(c&63)*2 + 1);
        sh[c ^ (r & 7)] = U.v;
    }
}

// ---- flat per-band barrier: 24 arrivals on one monotone counter ----
__device__ __forceinline__ void band_bar(unsigned* cnt, unsigned* ep, unsigned tgt){
    asm volatile("s_waitcnt vmcnt(0)" ::: "memory");
    __syncthreads();
    if (threadIdx.x == 0){
        unsigned old = __hip_atomic_fetch_add(cnt, 1u, __ATOMIC_RELAXED, __HIP_MEMORY_SCOPE_AGENT);
        if (old == tgt*BPB - 1u)
            __hip_atomic_store(ep, tgt, __ATOMIC_RELAXED, __HIP_MEMORY_SCOPE_AGENT);
        else
            while (__hip_atomic_load(ep, __ATOMIC_RELAXED, __HIP_MEMORY_SCOPE_AGENT) < tgt)
                __builtin_amdgcn_s_sleep(1);
    }
    __syncthreads();
}

// ---- PROBES: decompose phase cost ----
__global__ void probe_bar(unsigned* bar){
    int g = blockIdx.x & 7;
    unsigned* cnt = bar + g*32; unsigned* ep = cnt + 16;
    for (int p = 1; p <= PROBE_IT; ++p)
        band_bar(cnt, ep, (unsigned)p);
}
__global__ void probe_exch(unsigned* bar, const ull* src, ull* dst){
    __shared__ bf16x8 sh[2048];
    int g = blockIdx.x & 7;
    unsigned* cnt = bar + g*32; unsigned* ep = cnt + 16;
    int tid = threadIdx.x;
    for (int p = 1; p <= PROBE_IT; ++p){
        stage32(sh, src + (size_t)g*4096, tid);
        __syncthreads();
        union { bf16x8 v; ull u[2]; } R; R.v = sh[tid];
        cstore(dst + (size_t)blockIdx.x*256 + tid, R.u[0] + p);
        band_bar(cnt, ep, (unsigned)p);
    }
}

// ---- persistent 2-layer LSTM; 8 independent bands x 24 blocks ----
// band g = bid&7 (rows g*32..+31); t = bid>>3: t<8 -> L1 (wave: 32r x 16 packed-col-tiles? no:
// L1 wave owns jt0..jt0+3 (16 j x 4 gates), L2 wave owns jt0..jt0+1. Weights in VGPRs.
__launch_bounds__(256, 1)
__global__ void lstm_persistent(const float* __restrict__ x,
                                const float* __restrict__ wih1,
                                const float* __restrict__ b1s,
                                const float* __restrict__ b2s,
                                const __bf16* __restrict__ w1p,
                                const __bf16* __restrict__ w2p,
                                __bf16* __restrict__ h1b,
                                __bf16* __restrict__ h2b,
                                unsigned* __restrict__ bar)
{
    __shared__ bf16x8 sh[4096];   // 64 KB (L1 blocks use first half)
    const int bid = blockIdx.x;
    const int g   = bid & 7;
    const int t   = bid >> 3;     // 0..23
    unsigned* cnt = bar + g*32;
    unsigned* ep  = cnt + 16;

    const int tid  = threadIdx.x;
    const int v    = tid >> 6;
    const int lane = tid & 63;
    const int llo  = lane & 15, lhi = lane >> 4;
    const int sw   = llo & 7;

    const ull* h1u = (const ull*)h1b;
    const ull* h2u = (const ull*)h2b;
    const size_t bandoff = (size_t)g*32*128;
    const int HB = BHz/4;

    if (t < 8){
        // ---------------- layer 1: wave = 32 rows x jt0..jt0+3 ----------------
        const int jt0 = t*16 + v*4;
        bf16x8 wf[4][16];
        #pragma unroll
        for (int m = 0; m < 4; ++m)
            #pragma unroll
            for (int kb = 0; kb < 16; ++kb)
                wf[m][kb] = *reinterpret_cast<const bf16x8*>(
                    w1p + ((size_t)((jt0+m)*16 + kb)*64 + lane)*8);
        float wa[4][4], wb[4][4], bb[4][4];
        #pragma unroll
        for (int m = 0; m < 4; ++m)
            #pragma unroll
            for (int q = 0; q < 4; ++q){
                int col = q*512 + (jt0+m)*4 + lhi;
                wa[m][q] = wih1[col]; wb[m][q] = wih1[2048 + col]; bb[m][q] = b1s[col];
            }
        const float2* x2 = reinterpret_cast<const float2*>(x);
        float c1[4][2] = {{0,0},{0,0},{0,0},{0,0}};

        for (int p = 0; p <= Tz; ++p){
            if (p < Tz){
                stage32(sh, h1u + ((p+1)&1)*HB + bandoff, tid);
                __syncthreads();
                f32x4 acc[4][2];
                #pragma unroll
                for (int m = 0; m < 4; ++m){ acc[m][0] = (f32x4){0,0,0,0}; acc[m][1] = (f32x4){0,0,0,0}; }
                #pragma unroll
                for (int nt = 0; nt < 2; ++nt){
                    const int base = (nt*16 + llo) << 6;
                    #pragma unroll
                    for (int kb = 0; kb < 16; ++kb){
                        bf16x8 bf = sh[(base + kb*4 + lhi) ^ sw];
                        acc[0][nt] = MFMA16(wf[0][kb], bf, acc[0][nt]);
                        acc[1][nt] = MFMA16(wf[1][kb], bf, acc[1][nt]);
                        acc[2][nt] = MFMA16(wf[2][kb], bf, acc[2][nt]);
                        acc[3][nt] = MFMA16(wf[3][kb], bf, acc[3][nt]);
                    }
                }
                ull* h1n = (ull*)h1b + (p&1)*HB;
                #pragma unroll
                for (int nt = 0; nt < 2; ++nt){
                    int row = g*32 + nt*16 + llo;
                    float2 xv = x2[(size_t)row*Tz + p];
                    ull pk[4];
                    #pragma unroll
                    for (int m = 0; m < 4; ++m){
                        float gi = acc[m][nt][0] + xv.x*wa[m][0] + xv.y*wb[m][0] + bb[m][0];
                        float gf = acc[m][nt][1] + xv.x*wa[m][1] + xv.y*wb[m][1] + bb[m][1];
                        float gg = acc[m][nt][2] + xv.x*wa[m][2] + xv.y*wb[m][2] + bb[m][2];
                        float go = acc[m][nt][3] + xv.x*wa[m][3] + xv.y*wb[m][3] + bb[m][3];
                        float cn = sigf(gf)*c1[m][nt] + sigf(gi)*tanhf_(gg);
                        c1[m][nt] = cn;
                        __bf16 hv = (__bf16)(sigf(go)*tanhf_(cn));
                        unsigned hb_;
                        { union { __bf16 b; unsigned short s; } C; C.b = hv; hb_ = C.s; }
                        unsigned s1 = __shfl(hb_, llo+16, 64);
                        unsigned s2 = __shfl(hb_, llo+32, 64);
                        unsigned s3 = __shfl(hb_, llo+48, 64);
                        pk[m] = (ull)hb_ | ((ull)s1<<16) | ((ull)s2<<32) | ((ull)s3<<48);
                    }
                    if (lane < 16){
                        ull* dst = h1n + (size_t)row*128 + jt0;
                        cstore(dst,   pk[0]); cstore(dst+1, pk[1]);
                        cstore(dst+2, pk[2]); cstore(dst+3, pk[3]);
                    }
                }
            }
            band_bar(cnt, ep, (unsigned)(p+1));
        }
    } else {
        // ---------------- layer 2: wave = 32 rows x jt0..jt0+1, K=1024 ----------------
        const int u   = t - 8;               // 0..15
        const int jt0 = u*8 + v*2;
        bf16x8 wf[2][32];
        #pragma unroll
        for (int m = 0; m < 2; ++m)
            #pragma unroll
            for (int kb = 0; kb < 32; ++kb)
                wf[m][kb] = *reinterpret_cast<const bf16x8*>(
                    w2p + ((size_t)((jt0+m)*32 + kb)*64 + lane)*8);
        float bb2[2][4];
        #pragma unroll
        for (int m = 0; m < 2; ++m)
            #pragma unroll
            for (int q = 0; q < 4; ++q)
                bb2[m][q] = b2s[q*512 + (jt0+m)*4 + lhi];
        float c2[2][2] = {{0,0},{0,0}};

        for (int p = 0; p <= Tz; ++p){
            if (p >= 1){
                stage32(sh,        h1u + ((p+1)&1)*HB + bandoff, tid);   // h1[p-1]
                stage32(sh + 2048, h2u + (p&1)*HB     + bandoff, tid);   // h2[p-2]
                __syncthreads();
                f32x4 acc[2][2];
                acc[0][0]=(f32x4){0,0,0,0}; acc[0][1]=(f32x4){0,0,0,0};
                acc[1][0]=(f32x4){0,0,0,0}; acc[1][1]=(f32x4){0,0,0,0};
                #pragma unroll
                for (int nt = 0; nt < 2; ++nt){
                    const int base = (nt*16 + llo) << 6;
                    #pragma unroll
                    for (int kb = 0; kb < 16; ++kb){
                        bf16x8 bf = sh[(base + kb*4 + lhi) ^ sw];
                        acc[0][nt] = MFMA16(wf[0][kb], bf, acc[0][nt]);
                        acc[1][nt] = MFMA16(wf[1][kb], bf, acc[1][nt]);
                    }
                    #pragma unroll
                    for (int kb = 16; kb < 32; ++kb){
                        bf16x8 bf = sh[2048 + ((base + (kb-16)*4 + lhi) ^ sw)];
                        acc[0][nt] = MFMA16(wf[0][kb], bf, acc[0][nt]);
                        acc[1][nt] = MFMA16(wf[1][kb], bf, acc[1][nt]);
                    }
                }
                ull* h2n = (ull*)h2b + ((p+1)&1)*HB;
                #pragma unroll
                for (int nt = 0; nt < 2; ++nt){
                    int row = g*32 + nt*16 + llo;
                    ull pk[2];
                    #pragma unroll
                    for (int m = 0; m < 2; ++m){
                        float gi = acc[m][nt][0] + bb2[m][0];
                        float gf = acc[m][nt][1] + bb2[m][1];
                        float gg = acc[m][nt][2] + bb2[m][2];
                        float go = acc[m][nt][3] + bb2[m][3];
                        float cn = sigf(gf)*c2[m][nt] + sigf(gi)*tanhf_(gg);
                        c2[m][nt] = cn;
                        __bf16 hv = (__bf16)(sigf(go)*tanhf_(cn));
                        unsigned hb_;
                        { union { __bf16 b; unsigned short s; } C; C.b = hv; hb_ = C.s; }
                        unsigned s1 = __shfl(hb_, llo+16, 64);
                        unsigned s2 = __shfl(hb_, llo+32, 64);
                        unsigned s3 = __shfl(hb_, llo+48, 64);
                        pk[m] = (ull)hb_ | ((ull)s1<<16) | ((ull)s2<<32) | ((ull)s3<<48);
                    }
                    if (lane < 16){
                        ull* dst = h2n + (size_t)row*128 + jt0;
                        cstore(dst, pk[0]); cstore(dst+1, pk[1]);
                    }
                }
            }
            band_bar(cnt, ep, (unsigned)(p+1));
        }
    }
}

// ---- final logits + softmax ----
__global__ void logits_softmax(const __bf16* __restrict__ h2, const float* __restrict__ fcw,
                               const float* __restrict__ fcb, float* __restrict__ out)
{
    int row = blockIdx.x;
    int lane = threadIdx.x;
    float acc[11];
    #pragma unroll
    for (int o = 0; o < 11; ++o) acc[o] = 0.f;
    for (int it = 0; it < 8; ++it){
        int jj = it*64 + lane;
        float hv = (float)h2[row*512 + jj];
        #pragma unroll
        for (int o = 0; o < 11; ++o) acc[o] += hv * fcw[jj*11 + o];
    }
    #pragma unroll
    for (int o = 0; o < 11; ++o)
        for (int s = 32; s >= 1; s >>= 1) acc[o] += __shfl_xor(acc[o], s, 64);
    float m = -1e30f;
    #pragma unroll
    for (int o = 0; o < 11; ++o){ acc[o] += fcb[o]; m = fmaxf(m, acc[o]); }
    float ssum = 0.f;
    #pragma unroll
    for (int o = 0; o < 11; ++o){ acc[o] = __expf(acc[o] - m); ssum += acc[o]; }
    float inv = 1.0f/ssum;
    if (lane < 11) out[row*11 + lane] = acc[lane]*inv;
}

extern "C" void kernel_launch(void* const* d_in, const int* in_sizes, int n_in,
                              void* d_out, int out_size, void* d_ws, size_t ws_size,
                              hipStream_t stream)
{
    const float* x    = (const float*)d_in[0];
    const float* wih1 = (const float*)d_in[1];
    const float* whh1 = (const float*)d_in[2];
    const float* bih1 = (const float*)d_in[3];
    const float* bhh1 = (const float*)d_in[4];
    const float* wih2 = (const float*)d_in[5];
    const float* whh2 = (const float*)d_in[6];
    const float* bih2 = (const float*)d_in[7];
    const float* bhh2 = (const float*)d_in[8];
    const float* fcw  = (const float*)d_in[9];
    const float* fcb  = (const float*)d_in[10];
    float* out = (float*)d_out;

    char* p = (char*)d_ws;
    __bf16* w1p = (__bf16*)p;  p += (size_t)512*2048*2;   // 2 MB
    __bf16* w2p = (__bf16*)p;  p += (size_t)1024*2048*2;  // 4 MB
    float*  b1s = (float*)p;   p += 2048*4;
    float*  b2s = (float*)p;   p += 2048*4;
    __bf16* h1b = (__bf16*)p;  p += (size_t)2*BHz*2;      // 512 KB
    __bf16* h2b = (__bf16*)p;  p += (size_t)2*BHz*2;      // 512 KB
    unsigned* bar  = (unsigned*)p; p += 8*32*4;           // main barrier
    unsigned* pbar1 = (unsigned*)p; p += 8*32*4;          // probe barriers
    unsigned* pbar2 = (unsigned*)p; p += 8*32*4;
    ull* pscr = (ull*)p; p += (size_t)NBLK*256*8;         // 384 KB probe scratch

    hipMemsetAsync(h1b, 0, (size_t)2*BHz*2, stream);
    hipMemsetAsync(h2b, 0, (size_t)2*BHz*2, stream);
    hipMemsetAsync(bar,  0, 8*32*4, stream);
    hipMemsetAsync(pbar1, 0, 8*32*4, stream);
    hipMemsetAsync(pbar2, 0, 8*32*4, stream);
    pack_w1 <<<4096, 256, 0, stream>>>(whh1, w1p);
    pack_w2 <<<8192, 256, 0, stream>>>(wih2, whh2, w2p);
    pack_bias<<<8,   256, 0, stream>>>(bih1, bhh1, bih2, bhh2, b1s, b2s);

    // probes (128 phases each): decompose phase cost via their rocprof rows
    probe_bar <<<NBLK, 256, 0, stream>>>(pbar1);
    probe_exch<<<NBLK, 256, 0, stream>>>(pbar2, (const ull*)h1b, pscr);

    lstm_persistent<<<NBLK, 256, 0, stream>>>(x, wih1, b1s, b2s, w1p, w2p, h1b, h2b, bar);

    logits_softmax<<<256, 64, 0, stream>>>(h2b + BHz, fcw, fcb, out);
}

// Round 7
// 4396.160 us; speedup vs baseline: 2.0897x; 1.1632x over previous
//
#include <hip/hip_runtime.h>
#include <hip/hip_bf16.h>

#define Tz  512
#define Hz  512
#define BHz (256*512)
#define NBLK 192
#define HB4 (BHz/4)      // ull words per h buffer

typedef __bf16 bf16x8 __attribute__((ext_vector_type(8)));
typedef float  f32x4  __attribute__((ext_vector_type(4)));
typedef unsigned long long ull;

#define MFMA16(A,B,C) __builtin_amdgcn_mfma_f32_16x16x32_bf16(A,B,C,0,0,0)

__device__ __forceinline__ float sigf(float x){ return 1.0f/(1.0f+__expf(-x)); }
__device__ __forceinline__ float tanhf_(float x){ return 2.0f/(1.0f+__expf(-2.0f*x)) - 1.0f; }

// coherent (device-coherence-point) accesses
__device__ __forceinline__ ull cload(const ull* p){
    return __hip_atomic_load(p, __ATOMIC_RELAXED, __HIP_MEMORY_SCOPE_AGENT);
}
__device__ __forceinline__ void cstore(ull* p, ull v){
    __hip_atomic_store(p, v, __ATOMIC_RELAXED, __HIP_MEMORY_SCOPE_AGENT);
}
__device__ __forceinline__ unsigned cload32(const unsigned* p){
    return __hip_atomic_load(p, __ATOMIC_RELAXED, __HIP_MEMORY_SCOPE_AGENT);
}
__device__ __forceinline__ void cstore32(unsigned* p, unsigned v){
    __hip_atomic_store(p, v, __ATOMIC_RELAXED, __HIP_MEMORY_SCOPE_AGENT);
}

// ---- pack weights as MFMA A-operand frags (W^T), gate-interleaved (r5/r6-verified) ----
__global__ void pack_w1(const float* __restrict__ w, __bf16* __restrict__ out){
    int idx = blockIdx.x*256 + threadIdx.x;   // 1,048,576 = 128*16*64*8
    int i = idx & 7, lane = (idx>>3)&63, kb = (idx>>9)&15, jt = idx>>13;
    int k  = kb*32 + (lane>>4)*8 + i;
    int m  = lane & 15;
    int col = (m&3)*512 + jt*4 + (m>>2);
    out[idx] = (__bf16)w[k*2048 + col];
}
__global__ void pack_w2(const float* __restrict__ wih, const float* __restrict__ whh,
                        __bf16* __restrict__ out){
    int idx = blockIdx.x*256 + threadIdx.x;   // 2,097,152 = 128*32*64*8
    int i = idx & 7, lane = (idx>>3)&63, kb = (idx>>9)&31, jt = idx>>14;
    int k  = kb*32 + (lane>>4)*8 + i;
    int m  = lane & 15;
    int col = (m&3)*512 + jt*4 + (m>>2);
    float val = (k < 512) ? wih[k*2048 + col] : whh[(k-512)*2048 + col];
    out[idx] = (__bf16)val;
}
__global__ void pack_bias(const float* a, const float* b, const float* c, const float* d,
                          float* b1s, float* b2s){
    int i = blockIdx.x*256 + threadIdx.x;
    if (i < 2048){ b1s[i] = a[i]+b[i]; b2s[i] = c[i]+d[i]; }
}

// ---- stage 32 rows x 512 bf16 (32 KB) into LDS, XOR-swizzled ----
__device__ __forceinline__ void stage32(bf16x8* sh, const ull* src, int tid){
    #pragma unroll
    for (int i = 0; i < 8; ++i){
        int c = tid + 256*i;            // slot 0..2047
        int r = c >> 6;                 // row 0..31
        union { ull u[2]; bf16x8 v; } U;
        U.u[0] = cload(src + (size_t)r*128 + (size_t)(c&63)*2);
        U.u[1] = cload(src + (size_t)r*128 + (size_t)(c&63)*2 + 1);
        sh[c ^ (r & 7)] = U.v;
    }
}

// ---- dataflow wait: lanes 0..7 poll L1 flags to tgtA, lanes 8..23 poll L2 flags to tgtB ----
// flags are monotone per-block epochs, one 64B line each; no RMWs, parallel arrivals.
__device__ __forceinline__ void wait_flags(const unsigned* fbase, int lane,
                                           unsigned tgtA, unsigned tgtB){
    if (lane < 24){
        const unsigned* fp = fbase + lane*16;
        unsigned tgt = (lane < 8) ? tgtA : tgtB;
        while (cload32(fp) < tgt) { }
    }
}

// ---- persistent 2-layer LSTM; 8 bands x 24 blocks; flag-based dataflow sync ----
// band g = bid&7 (rows g*32..+31); t = bid>>3: t<8 -> L1, else L2. Weights in VGPRs.
// h1/h2 are 4-deep rings: h*[s] lives in buf s&3; buf 3 zeroed = step -1.
__launch_bounds__(256, 1)
__global__ void lstm_persistent(const float* __restrict__ x,
                                const float* __restrict__ wih1,
                                const float* __restrict__ b1s,
                                const float* __restrict__ b2s,
                                const __bf16* __restrict__ w1p,
                                const __bf16* __restrict__ w2p,
                                __bf16* __restrict__ h1b,   // 4 x [B][H]
                                __bf16* __restrict__ h2b,   // 4 x [B][H]
                                unsigned* __restrict__ flags)
{
    __shared__ bf16x8 sh[4096];   // 64 KB
    const int bid = blockIdx.x;
    const int g   = bid & 7;
    const int t   = bid >> 3;     // 0..23
    unsigned* fbase = flags + g*384;   // 24 flags x 16 words

    const int tid  = threadIdx.x;
    const int v    = tid >> 6;
    const int lane = tid & 63;
    const int llo  = lane & 15, lhi = lane >> 4;
    const int sw   = llo & 7;

    const ull* h1u = (const ull*)h1b;
    const ull* h2u = (const ull*)h2b;
    const size_t bandoff = (size_t)g*32*128;

    if (t < 8){
        // ---------------- layer 1: wave = 32 rows x jt0..jt0+3 ----------------
        const int jt0 = t*16 + v*4;
        bf16x8 wf[4][16];
        #pragma unroll
        for (int m = 0; m < 4; ++m)
            #pragma unroll
            for (int kb = 0; kb < 16; ++kb)
                wf[m][kb] = *reinterpret_cast<const bf16x8*>(
                    w1p + ((size_t)((jt0+m)*16 + kb)*64 + lane)*8);
        float wa[4][4], wb[4][4], bb[4][4];
        #pragma unroll
        for (int m = 0; m < 4; ++m)
            #pragma unroll
            for (int q = 0; q < 4; ++q){
                int col = q*512 + (jt0+m)*4 + lhi;
                wa[m][q] = wih1[col]; wb[m][q] = wih1[2048 + col]; bb[m][q] = b1s[col];
            }
        const float2* x2 = reinterpret_cast<const float2*>(x);
        float c1[4][2] = {{0,0},{0,0},{0,0},{0,0}};

        for (int p = 0; p < Tz; ++p){
            // need: mates' h1[p-1] (L1 flags >= p); anti-dep on buf p&3 (L2 flags >= p-2)
            wait_flags(fbase, lane, (unsigned)p, (p >= 2) ? (unsigned)(p-2) : 0u);
            stage32(sh, h1u + (size_t)((p+3)&3)*HB4 + bandoff, tid);
            __syncthreads();
            f32x4 acc[4][2];
            #pragma unroll
            for (int m = 0; m < 4; ++m){ acc[m][0] = (f32x4){0,0,0,0}; acc[m][1] = (f32x4){0,0,0,0}; }
            #pragma unroll
            for (int nt = 0; nt < 2; ++nt){
                const int base = (nt*16 + llo) << 6;
                #pragma unroll
                for (int kb = 0; kb < 16; ++kb){
                    bf16x8 bf = sh[(base + kb*4 + lhi) ^ sw];
                    acc[0][nt] = MFMA16(wf[0][kb], bf, acc[0][nt]);
                    acc[1][nt] = MFMA16(wf[1][kb], bf, acc[1][nt]);
                    acc[2][nt] = MFMA16(wf[2][kb], bf, acc[2][nt]);
                    acc[3][nt] = MFMA16(wf[3][kb], bf, acc[3][nt]);
                }
            }
            ull* h1n = (ull*)h1b + (size_t)(p&3)*HB4;
            #pragma unroll
            for (int nt = 0; nt < 2; ++nt){
                int row = g*32 + nt*16 + llo;
                float2 xv = x2[(size_t)row*Tz + p];
                ull pk[4];
                #pragma unroll
                for (int m = 0; m < 4; ++m){
                    float gi = acc[m][nt][0] + xv.x*wa[m][0] + xv.y*wb[m][0] + bb[m][0];
                    float gf = acc[m][nt][1] + xv.x*wa[m][1] + xv.y*wb[m][1] + bb[m][1];
                    float gg = acc[m][nt][2] + xv.x*wa[m][2] + xv.y*wb[m][2] + bb[m][2];
                    float go = acc[m][nt][3] + xv.x*wa[m][3] + xv.y*wb[m][3] + bb[m][3];
                    float cn = sigf(gf)*c1[m][nt] + sigf(gi)*tanhf_(gg);
                    c1[m][nt] = cn;
                    __bf16 hv = (__bf16)(sigf(go)*tanhf_(cn));
                    unsigned hb_;
                    { union { __bf16 b; unsigned short s; } C; C.b = hv; hb_ = C.s; }
                    unsigned s1 = __shfl(hb_, llo+16, 64);
                    unsigned s2 = __shfl(hb_, llo+32, 64);
                    unsigned s3 = __shfl(hb_, llo+48, 64);
                    pk[m] = (ull)hb_ | ((ull)s1<<16) | ((ull)s2<<32) | ((ull)s3<<48);
                }
                if (lane < 16){
                    ull* dst = h1n + (size_t)row*128 + jt0;
                    cstore(dst,   pk[0]); cstore(dst+1, pk[1]);
                    cstore(dst+2, pk[2]); cstore(dst+3, pk[3]);
                }
            }
            asm volatile("s_waitcnt vmcnt(0)" ::: "memory");
            __syncthreads();
            if (tid == 0) cstore32(fbase + t*16, (unsigned)(p+1));
        }
    } else {
        // ---------------- layer 2: wave = 32 rows x jt0..jt0+1, K=1024 ----------------
        const int u   = t - 8;               // 0..15
        const int jt0 = u*8 + v*2;
        bf16x8 wf[2][32];
        #pragma unroll
        for (int m = 0; m < 2; ++m)
            #pragma unroll
            for (int kb = 0; kb < 32; ++kb)
                wf[m][kb] = *reinterpret_cast<const bf16x8*>(
                    w2p + ((size_t)((jt0+m)*32 + kb)*64 + lane)*8);
        float bb2[2][4];
        #pragma unroll
        for (int m = 0; m < 2; ++m)
            #pragma unroll
            for (int q = 0; q < 4; ++q)
                bb2[m][q] = b2s[q*512 + (jt0+m)*4 + lhi];
        float c2[2][2] = {{0,0},{0,0}};

        for (int q = 1; q <= Tz; ++q){
            // need: h1[q-1] (L1 flags >= q); mates' h2[q-2] (L2 flags >= q-1)
            wait_flags(fbase, lane, (unsigned)q, (unsigned)(q-1));
            stage32(sh,        h1u + (size_t)((q+3)&3)*HB4 + bandoff, tid);   // h1[q-1]
            stage32(sh + 2048, h2u + (size_t)((q+2)&3)*HB4 + bandoff, tid);   // h2[q-2]
            __syncthreads();
            f32x4 acc[2][2];
            acc[0][0]=(f32x4){0,0,0,0}; acc[0][1]=(f32x4){0,0,0,0};
            acc[1][0]=(f32x4){0,0,0,0}; acc[1][1]=(f32x4){0,0,0,0};
            #pragma unroll
            for (int nt = 0; nt < 2; ++nt){
                const int base = (nt*16 + llo) << 6;
                #pragma unroll
                for (int kb = 0; kb < 16; ++kb){
                    bf16x8 bf = sh[(base + kb*4 + lhi) ^ sw];
                    acc[0][nt] = MFMA16(wf[0][kb], bf, acc[0][nt]);
                    acc[1][nt] = MFMA16(wf[1][kb], bf, acc[1][nt]);
                }
                #pragma unroll
                for (int kb = 16; kb < 32; ++kb){
                    bf16x8 bf = sh[2048 + ((base + (kb-16)*4 + lhi) ^ sw)];
                    acc[0][nt] = MFMA16(wf[0][kb], bf, acc[0][nt]);
                    acc[1][nt] = MFMA16(wf[1][kb], bf, acc[1][nt]);
                }
            }
            ull* h2n = (ull*)h2b + (size_t)((q+3)&3)*HB4;   // h2[q-1]
            #pragma unroll
            for (int nt = 0; nt < 2; ++nt){
                int row = g*32 + nt*16 + llo;
                ull pk[2];
                #pragma unroll
                for (int m = 0; m < 2; ++m){
                    float gi = acc[m][nt][0] + bb2[m][0];
                    float gf = acc[m][nt][1] + bb2[m][1];
                    float gg = acc[m][nt][2] + bb2[m][2];
                    float go = acc[m][nt][3] + bb2[m][3];
                    float cn = sigf(gf)*c2[m][nt] + sigf(gi)*tanhf_(gg);
                    c2[m][nt] = cn;
                    __bf16 hv = (__bf16)(sigf(go)*tanhf_(cn));
                    unsigned hb_;
                    { union { __bf16 b; unsigned short s; } C; C.b = hv; hb_ = C.s; }
                    unsigned s1 = __shfl(hb_, llo+16, 64);
                    unsigned s2 = __shfl(hb_, llo+32, 64);
                    unsigned s3 = __shfl(hb_, llo+48, 64);
                    pk[m] = (ull)hb_ | ((ull)s1<<16) | ((ull)s2<<32) | ((ull)s3<<48);
                }
                if (lane < 16){
                    ull* dst = h2n + (size_t)row*128 + jt0;
                    cstore(dst, pk[0]); cstore(dst+1, pk[1]);
                }
            }
            asm volatile("s_waitcnt vmcnt(0)" ::: "memory");
            __syncthreads();
            if (tid == 0) cstore32(fbase + t*16, (unsigned)q);
        }
    }
}

// ---- final logits + softmax ----
__global__ void logits_softmax(const __bf16* __restrict__ h2, const float* __restrict__ fcw,
                               const float* __restrict__ fcb, float* __restrict__ out)
{
    int row = blockIdx.x;
    int lane = threadIdx.x;
    float acc[11];
    #pragma unroll
    for (int o = 0; o < 11; ++o) acc[o] = 0.f;
    for (int it = 0; it < 8; ++it){
        int jj = it*64 + lane;
        float hv = (float)h2[row*512 + jj];
        #pragma unroll
        for (int o = 0; o < 11; ++o) acc[o] += hv * fcw[jj*11 + o];
    }
    #pragma unroll
    for (int o = 0; o < 11; ++o)
        for (int s = 32; s >= 1; s >>= 1) acc[o] += __shfl_xor(acc[o], s, 64);
    float m = -1e30f;
    #pragma unroll
    for (int o = 0; o < 11; ++o){ acc[o] += fcb[o]; m = fmaxf(m, acc[o]); }
    float ssum = 0.f;
    #pragma unroll
    for (int o = 0; o < 11; ++o){ acc[o] = __expf(acc[o] - m); ssum += acc[o]; }
    float inv = 1.0f/ssum;
    if (lane < 11) out[row*11 + lane] = acc[lane]*inv;
}

extern "C" void kernel_launch(void* const* d_in, const int* in_sizes, int n_in,
                              void* d_out, int out_size, void* d_ws, size_t ws_size,
                              hipStream_t stream)
{
    const float* x    = (const float*)d_in[0];
    const float* wih1 = (const float*)d_in[1];
    const float* whh1 = (const float*)d_in[2];
    const float* bih1 = (const float*)d_in[3];
    const float* bhh1 = (const float*)d_in[4];
    const float* wih2 = (const float*)d_in[5];
    const float* whh2 = (const float*)d_in[6];
    const float* bih2 = (const float*)d_in[7];
    const float* bhh2 = (const float*)d_in[8];
    const float* fcw  = (const float*)d_in[9];
    const float* fcb  = (const float*)d_in[10];
    float* out = (float*)d_out;

    char* p = (char*)d_ws;
    __bf16* w1p = (__bf16*)p;  p += (size_t)512*2048*2;   // 2 MB
    __bf16* w2p = (__bf16*)p;  p += (size_t)1024*2048*2;  // 4 MB
    float*  b1s = (float*)p;   p += 2048*4;
    float*  b2s = (float*)p;   p += 2048*4;
    __bf16* h1b = (__bf16*)p;  p += (size_t)4*BHz*2;      // 1 MB (4-deep ring)
    __bf16* h2b = (__bf16*)p;  p += (size_t)4*BHz*2;      // 1 MB
    unsigned* flags = (unsigned*)p; p += 8*384*4;         // 12 KB

    hipMemsetAsync(h1b, 0, (size_t)4*BHz*2, stream);
    hipMemsetAsync(h2b, 0, (size_t)4*BHz*2, stream);
    hipMemsetAsync(flags, 0, 8*384*4, stream);
    pack_w1 <<<4096, 256, 0, stream>>>(whh1, w1p);
    pack_w2 <<<8192, 256, 0, stream>>>(wih2, whh2, w2p);
    pack_bias<<<8,   256, 0, stream>>>(bih1, bhh1, bih2, bhh2, b1s, b2s);

    lstm_persistent<<<NBLK, 256, 0, stream>>>(x, wih1, b1s, b2s, w1p, w2p, h1b, h2b, flags);

    // h2[T-1] lives in ring buffer 3 (511 & 3 == 3)
    logits_softmax<<<256, 64, 0, stream>>>(h2b + (size_t)3*BHz, fcw, fcb, out);
}

// Round 9
// 3169.128 us; speedup vs baseline: 2.8988x; 1.3872x over previous
//
#include <hip/hip_runtime.h>
#include <hip/hip_bf16.h>

#define Tz  512
#define Hz  512
#define BHz (256*512)
#define NBLK 192
#define HB4 (BHz/4)      // ull words per h buffer

typedef __bf16 bf16x8 __attribute__((ext_vector_type(8)));
typedef float  f32x4  __attribute__((ext_vector_type(4)));
typedef unsigned u32x4 __attribute__((ext_vector_type(4)));
typedef unsigned long long ull;

#define MFMA16(A,B,C) __builtin_amdgcn_mfma_f32_16x16x32_bf16(A,B,C,0,0,0)

__device__ __forceinline__ float sigf(float x){ return 1.0f/(1.0f+__expf(-x)); }
__device__ __forceinline__ float tanhf_(float x){ return 2.0f/(1.0f+__expf(-2.0f*x)) - 1.0f; }

__device__ __forceinline__ unsigned cload32(const unsigned* p){
    return __hip_atomic_load(p, __ATOMIC_RELAXED, __HIP_MEMORY_SCOPE_AGENT);
}
__device__ __forceinline__ void cstore32(unsigned* p, unsigned v){
    __hip_atomic_store(p, v, __ATOMIC_RELAXED, __HIP_MEMORY_SCOPE_AGENT);
}

// ---- pack weights as MFMA A-operand frags (W^T), gate-interleaved (r5-r7 verified) ----
__global__ void pack_w1(const float* __restrict__ w, __bf16* __restrict__ out){
    int idx = blockIdx.x*256 + threadIdx.x;   // 1,048,576 = 128*16*64*8
    int i = idx & 7, lane = (idx>>3)&63, kb = (idx>>9)&15, jt = idx>>13;
    int k  = kb*32 + (lane>>4)*8 + i;
    int m  = lane & 15;
    int col = (m&3)*512 + jt*4 + (m>>2);
    out[idx] = (__bf16)w[k*2048 + col];
}
__global__ void pack_w2(const float* __restrict__ wih, const float* __restrict__ whh,
                        __bf16* __restrict__ out){
    int idx = blockIdx.x*256 + threadIdx.x;   // 2,097,152 = 128*32*64*8
    int i = idx & 7, lane = (idx>>3)&63, kb = (idx>>9)&31, jt = idx>>14;
    int k  = kb*32 + (lane>>4)*8 + i;
    int m  = lane & 15;
    int col = (m&3)*512 + jt*4 + (m>>2);
    float val = (k < 512) ? wih[k*2048 + col] : whh[(k-512)*2048 + col];
    out[idx] = (__bf16)val;
}
__global__ void pack_bias(const float* a, const float* b, const float* c, const float* d,
                          float* b1s, float* b2s){
    int i = blockIdx.x*256 + threadIdx.x;
    if (i < 2048){ b1s[i] = a[i]+b[i]; b2s[i] = c[i]+d[i]; }
}

// ---- 16B coherent staging: issue 8 dwordx4 (L1/L2-bypass), drain once, LDS-write swizzled ----
__device__ __forceinline__ void issue8(u32x4* r, const ull* src, int tid){
    #pragma unroll
    for (int i = 0; i < 8; ++i){
        int c = tid + 256*i;
        const ull* p = src + (size_t)(c>>6)*128 + (size_t)(c&63)*2;
        asm volatile("global_load_dwordx4 %0, %1, off sc0 sc1" : "=v"(r[i]) : "v"(p) : "memory");
    }
}
__device__ __forceinline__ void write8(bf16x8* sh, const u32x4* r, int tid){
    #pragma unroll
    for (int i = 0; i < 8; ++i){
        int c = tid + 256*i;
        union { u32x4 u; bf16x8 v; } U; U.u = r[i];
        sh[c ^ ((c>>6) & 7)] = U.v;
    }
}
#define DRAIN() do { asm volatile("s_waitcnt vmcnt(0)" ::: "memory"); \
                     __builtin_amdgcn_sched_barrier(0); } while(0)

__device__ __forceinline__ void cstore128(ull* p, ull lo, ull hi){
    union { ull q2[2]; u32x4 u; } S; S.q2[0] = lo; S.q2[1] = hi;
    asm volatile("global_store_dwordx4 %0, %1, off sc0 sc1" :: "v"(p), "v"(S.u) : "memory");
}

// ---- wave-0-only flag polls (other waves keep loads in flight), raw barrier ----
__device__ __forceinline__ void pollL1(const unsigned* fbase, int tid, unsigned tgt){
    if (tid < 8){ const unsigned* fp = fbase + tid*16;
        while (cload32(fp) < tgt) {} }
    __builtin_amdgcn_s_barrier();
}
__device__ __forceinline__ void pollL2(const unsigned* fbase, int tid, unsigned tgt){
    if (tid < 16){ const unsigned* fp = fbase + (8+tid)*16;
        while (cload32(fp) < tgt) {} }
    __builtin_amdgcn_s_barrier();
}

// ---- persistent 2-layer LSTM; 8 bands x 24 blocks; flag dataflow; 4-deep h rings ----
__launch_bounds__(256, 1)
__global__ void lstm_persistent(const float* __restrict__ x,
                                const float* __restrict__ wih1,
                                const float* __restrict__ b1s,
                                const float* __restrict__ b2s,
                                const __bf16* __restrict__ w1p,
                                const __bf16* __restrict__ w2p,
                                __bf16* __restrict__ h1b,   // 4 x [B][H]
                                __bf16* __restrict__ h2b,   // 4 x [B][H]
                                unsigned* __restrict__ flags)
{
    __shared__ bf16x8 sh[4096];   // 64 KB
    const int bid = blockIdx.x;
    const int g   = bid & 7;
    const int t   = bid >> 3;     // 0..23
    unsigned* fbase = flags + g*384;

    const int tid  = threadIdx.x;
    const int v    = tid >> 6;
    const int lane = tid & 63;
    const int llo  = lane & 15, lhi = lane >> 4;
    const int sw   = llo & 7;

    const ull* h1u = (const ull*)h1b;
    const ull* h2u = (const ull*)h2b;
    const size_t bandoff = (size_t)g*32*128;

    if (t < 8){
        // ---------------- layer 1: wave = 32 rows x jt0..jt0+3 ----------------
        const int jt0 = t*16 + v*4;
        bf16x8 wf[4][16];
        #pragma unroll
        for (int m = 0; m < 4; ++m)
            #pragma unroll
            for (int kb = 0; kb < 16; ++kb)
                wf[m][kb] = *reinterpret_cast<const bf16x8*>(
                    w1p + ((size_t)((jt0+m)*16 + kb)*64 + lane)*8);
        float wa[4][4], wb[4][4], bb[4][4];
        #pragma unroll
        for (int m = 0; m < 4; ++m)
            #pragma unroll
            for (int q = 0; q < 4; ++q){
                int col = q*512 + (jt0+m)*4 + lhi;
                wa[m][q] = wih1[col]; wb[m][q] = wih1[2048 + col]; bb[m][q] = b1s[col];
            }
        const float2* x2 = reinterpret_cast<const float2*>(x);
        float c1[4][2] = {{0,0},{0,0},{0,0},{0,0}};

        for (int p = 0; p < Tz; ++p){
            pollL1(fbase, tid, (unsigned)p);                    // mates' h1[p-1] ready
            u32x4 rA[8];
            issue8(rA, h1u + (size_t)((p+3)&3)*HB4 + bandoff, tid);
            DRAIN();
            write8(sh, rA, tid);
            __syncthreads();
            f32x4 acc[4][2];
            #pragma unroll
            for (int m = 0; m < 4; ++m){ acc[m][0] = (f32x4){0,0,0,0}; acc[m][1] = (f32x4){0,0,0,0}; }
            #pragma unroll
            for (int nt = 0; nt < 2; ++nt){
                const int base = (nt*16 + llo) << 6;
                #pragma unroll
                for (int kb = 0; kb < 16; ++kb){
                    bf16x8 bf = sh[(base + kb*4 + lhi) ^ sw];
                    acc[0][nt] = MFMA16(wf[0][kb], bf, acc[0][nt]);
                    acc[1][nt] = MFMA16(wf[1][kb], bf, acc[1][nt]);
                    acc[2][nt] = MFMA16(wf[2][kb], bf, acc[2][nt]);
                    acc[3][nt] = MFMA16(wf[3][kb], bf, acc[3][nt]);
                }
            }
            // gate math
            ull pkk[2][4];
            #pragma unroll
            for (int nt = 0; nt < 2; ++nt){
                int row = g*32 + nt*16 + llo;
                float2 xv = x2[(size_t)row*Tz + p];
                #pragma unroll
                for (int m = 0; m < 4; ++m){
                    float gi = acc[m][nt][0] + xv.x*wa[m][0] + xv.y*wb[m][0] + bb[m][0];
                    float gf = acc[m][nt][1] + xv.x*wa[m][1] + xv.y*wb[m][1] + bb[m][1];
                    float gg = acc[m][nt][2] + xv.x*wa[m][2] + xv.y*wb[m][2] + bb[m][2];
                    float go = acc[m][nt][3] + xv.x*wa[m][3] + xv.y*wb[m][3] + bb[m][3];
                    float cn = sigf(gf)*c1[m][nt] + sigf(gi)*tanhf_(gg);
                    c1[m][nt] = cn;
                    __bf16 hv = (__bf16)(sigf(go)*tanhf_(cn));
                    unsigned hb_;
                    { union { __bf16 b; unsigned short s; } C; C.b = hv; hb_ = C.s; }
                    unsigned s1 = __shfl(hb_, llo+16, 64);
                    unsigned s2 = __shfl(hb_, llo+32, 64);
                    unsigned s3 = __shfl(hb_, llo+48, 64);
                    pkk[nt][m] = (ull)hb_ | ((ull)s1<<16) | ((ull)s2<<32) | ((ull)s3<<48);
                }
            }
            pollL2(fbase, tid, (p >= 3) ? (unsigned)(p-3) : 0u); // anti-dep on buf p&3
            ull* h1n = (ull*)h1b + (size_t)(p&3)*HB4;
            if (lane < 16){
                #pragma unroll
                for (int nt = 0; nt < 2; ++nt){
                    int row = g*32 + nt*16 + llo;
                    ull* dst = h1n + (size_t)row*128 + jt0;
                    cstore128(dst,     pkk[nt][0], pkk[nt][1]);
                    cstore128(dst + 2, pkk[nt][2], pkk[nt][3]);
                }
            }
            __syncthreads();                                     // drains all waves' stores
            if (tid == 0) cstore32(fbase + t*16, (unsigned)(p+1));
        }
    } else {
        // ---------------- layer 2: wave = 32 rows x jt0..jt0+1, K=1024 ----------------
        const int u   = t - 8;               // 0..15
        const int jt0 = u*8 + v*2;
        bf16x8 wf[2][32];
        #pragma unroll
        for (int m = 0; m < 2; ++m)
            #pragma unroll
            for (int kb = 0; kb < 32; ++kb)
                wf[m][kb] = *reinterpret_cast<const bf16x8*>(
                    w2p + ((size_t)((jt0+m)*32 + kb)*64 + lane)*8);
        float bb2[2][4];
        #pragma unroll
        for (int m = 0; m < 2; ++m)
            #pragma unroll
            for (int q = 0; q < 4; ++q)
                bb2[m][q] = b2s[q*512 + (jt0+m)*4 + lhi];
        float c2[2][2] = {{0,0},{0,0}};

        for (int q = 1; q <= Tz; ++q){
            pollL2(fbase, tid, (unsigned)(q-1));                 // mates' h2[q-2] ready
            u32x4 rB[8];
            issue8(rB, h2u + (size_t)((q+2)&3)*HB4 + bandoff, tid);   // h2[q-2] (in flight)
            pollL1(fbase, tid, (unsigned)q);                     // fresh h1[q-1]; overlaps rB
            u32x4 rA[8];
            issue8(rA, h1u + (size_t)((q+3)&3)*HB4 + bandoff, tid);
            DRAIN();
            write8(sh,        rA, tid);
            write8(sh + 2048, rB, tid);
            __syncthreads();
            f32x4 acc[2][2];
            acc[0][0]=(f32x4){0,0,0,0}; acc[0][1]=(f32x4){0,0,0,0};
            acc[1][0]=(f32x4){0,0,0,0}; acc[1][1]=(f32x4){0,0,0,0};
            #pragma unroll
            for (int nt = 0; nt < 2; ++nt){
                const int base = (nt*16 + llo) << 6;
                #pragma unroll
                for (int kb = 0; kb < 16; ++kb){
                    bf16x8 bf = sh[(base + kb*4 + lhi) ^ sw];
                    acc[0][nt] = MFMA16(wf[0][kb], bf, acc[0][nt]);
                    acc[1][nt] = MFMA16(wf[1][kb], bf, acc[1][nt]);
                }
                #pragma unroll
                for (int kb = 16; kb < 32; ++kb){
                    bf16x8 bf = sh[2048 + ((base + (kb-16)*4 + lhi) ^ sw)];
                    acc[0][nt] = MFMA16(wf[0][kb], bf, acc[0][nt]);
                    acc[1][nt] = MFMA16(wf[1][kb], bf, acc[1][nt]);
                }
            }
            ull* h2n = (ull*)h2b + (size_t)((q+3)&3)*HB4;   // h2[q-1]
            #pragma unroll
            for (int nt = 0; nt < 2; ++nt){
                int row = g*32 + nt*16 + llo;
                ull pk[2];
                #pragma unroll
                for (int m = 0; m < 2; ++m){
                    float gi = acc[m][nt][0] + bb2[m][0];
                    float gf = acc[m][nt][1] + bb2[m][1];
                    float gg = acc[m][nt][2] + bb2[m][2];
                    float go = acc[m][nt][3] + bb2[m][3];
                    float cn = sigf(gf)*c2[m][nt] + sigf(gi)*tanhf_(gg);
                    c2[m][nt] = cn;
                    __bf16 hv = (__bf16)(sigf(go)*tanhf_(cn));
                    unsigned hb_;
                    { union { __bf16 b; unsigned short s; } C; C.b = hv; hb_ = C.s; }
                    unsigned s1 = __shfl(hb_, llo+16, 64);
                    unsigned s2 = __shfl(hb_, llo+32, 64);
                    unsigned s3 = __shfl(hb_, llo+48, 64);
                    pk[m] = (ull)hb_ | ((ull)s1<<16) | ((ull)s2<<32) | ((ull)s3<<48);
                }
                if (lane < 16){
                    ull* dst = h2n + (size_t)row*128 + jt0;
                    cstore128(dst, pk[0], pk[1]);
                }
            }
            __syncthreads();                                     // drains stores
            if (tid == 0) cstore32(fbase + t*16, (unsigned)q);
        }
    }
}

// ---- final logits + softmax ----
__global__ void logits_softmax(const __bf16* __restrict__ h2, const float* __restrict__ fcw,
                               const float* __restrict__ fcb, float* __restrict__ out)
{
    int row = blockIdx.x;
    int lane = threadIdx.x;
    float acc[11];
    #pragma unroll
    for (int o = 0; o < 11; ++o) acc[o] = 0.f;
    for (int it = 0; it < 8; ++it){
        int jj = it*64 + lane;
        float hv = (float)h2[row*512 + jj];
        #pragma unroll
        for (int o = 0; o < 11; ++o) acc[o] += hv * fcw[jj*11 + o];
    }
    #pragma unroll
    for (int o = 0; o < 11; ++o)
        for (int s = 32; s >= 1; s >>= 1) acc[o] += __shfl_xor(acc[o], s, 64);
    float m = -1e30f;
    #pragma unroll
    for (int o = 0; o < 11; ++o){ acc[o] += fcb[o]; m = fmaxf(m, acc[o]); }
    float ssum = 0.f;
    #pragma unroll
    for (int o = 0; o < 11; ++o){ acc[o] = __expf(acc[o] - m); ssum += acc[o]; }
    float inv = 1.0f/ssum;
    if (lane < 11) out[row*11 + lane] = acc[lane]*inv;
}

extern "C" void kernel_launch(void* const* d_in, const int* in_sizes, int n_in,
                              void* d_out, int out_size, void* d_ws, size_t ws_size,
                              hipStream_t stream)
{
    const float* x    = (const float*)d_in[0];
    const float* wih1 = (const float*)d_in[1];
    const float* whh1 = (const float*)d_in[2];
    const float* bih1 = (const float*)d_in[3];
    const float* bhh1 = (const float*)d_in[4];
    const float* wih2 = (const float*)d_in[5];
    const float* whh2 = (const float*)d_in[6];
    const float* bih2 = (const float*)d_in[7];
    const float* bhh2 = (const float*)d_in[8];
    const float* fcw  = (const float*)d_in[9];
    const float* fcb  = (const float*)d_in[10];
    float* out = (float*)d_out;

    char* p = (char*)d_ws;
    __bf16* w1p = (__bf16*)p;  p += (size_t)512*2048*2;   // 2 MB
    __bf16* w2p = (__bf16*)p;  p += (size_t)1024*2048*2;  // 4 MB
    float*  b1s = (float*)p;   p += 2048*4;
    float*  b2s = (float*)p;   p += 2048*4;
    __bf16* h1b = (__bf16*)p;  p += (size_t)4*BHz*2;      // 1 MB (4-deep ring)
    __bf16* h2b = (__bf16*)p;  p += (size_t)4*BHz*2;      // 1 MB
    unsigned* flags = (unsigned*)p; p += 8*384*4;         // 12 KB

    (void)hipMemsetAsync(h1b, 0, (size_t)4*BHz*2, stream);
    (void)hipMemsetAsync(h2b, 0, (size_t)4*BHz*2, stream);
    (void)hipMemsetAsync(flags, 0, 8*384*4, stream);
    pack_w1 <<<4096, 256, 0, stream>>>(whh1, w1p);
    pack_w2 <<<8192, 256, 0, stream>>>(wih2, whh2, w2p);
    pack_bias<<<8,   256, 0, stream>>>(bih1, bhh1, bih2, bhh2, b1s, b2s);

    lstm_persistent<<<NBLK, 256, 0, stream>>>(x, wih1, b1s, b2s, w1p, w2p, h1b, h2b, flags);

    // h2[T-1] lives in ring buffer 3 (511 & 3 == 3)
    logits_softmax<<<256, 64, 0, stream>>>(h2b + (size_t)3*BHz, fcw, fcb, out);
}